// Round 11
// baseline (1875.183 us; speedup 1.0000x reference)
//
#include <hip/hip_runtime.h>
#include <hip/hip_bf16.h>
#include <hip/hip_fp16.h>
#include <math.h>

// ---------------------------------------------------------------------------
// MolGAT: 3x GATv2 (heads=1, D=64) + MLP(64->128->64->1, BN train-stats) +
// global mean pool over G=256 graphs.
// R10: mlp back to R8's non-paneled shape (R9 paneling: 137->177us, WRITE
// doubled); k4 loop FULLY unrolled so the compiler hoists the 64 independent
// row loads (kernel was latency-bound: VALUBusy 9%, hbm 7%). BN coeff fetch
// hoisted out of the row loop; stats scratch aliases dead sW. Single-pass
// grids (one row-tile per block). Race-free class unchanged (6/6 replay
// passes: no in-loop LDS row staging).
// ---------------------------------------------------------------------------

#define BSHIFT 9
#define BSIZE  512   // nodes per bucket
#define STAGE_CAP 24576

// ---------------- bucketed CSR build (unchanged, replay-proven) ----------------

__global__ __launch_bounds__(256) void k_bcount(const int* __restrict__ dstA,
                                                int* __restrict__ bcnt,
                                                int nE, int n) {
    __shared__ int h[512];
    int t = threadIdx.x;
    h[t] = 0; h[t + 256] = 0;
    __syncthreads();
    int tot = nE + n;
    for (int i = blockIdx.x * 256 + t; i < tot; i += gridDim.x * 256) {
        int d = (i < nE) ? dstA[i] : (i - nE);   // self loops appended
        atomicAdd(&h[d >> BSHIFT], 1);
    }
    __syncthreads();
    if (h[t])       atomicAdd(&bcnt[t], h[t]);
    if (h[t + 256]) atomicAdd(&bcnt[t + 256], h[t + 256]);
}

__global__ __launch_bounds__(512) void k_bscan(const int* __restrict__ bcnt,
                                               int* __restrict__ bbase,
                                               int* __restrict__ bcur,
                                               int* __restrict__ rowptr,
                                               int nb, int n, int etot) {
    __shared__ int buf[512];
    int t = threadIdx.x;
    int v = (t < nb) ? bcnt[t] : 0;
    buf[t] = v;
    __syncthreads();
    for (int off = 1; off < 512; off <<= 1) {
        int x = (t >= off) ? buf[t - off] : 0;
        __syncthreads();
        buf[t] += x;
        __syncthreads();
    }
    if (t < nb) { int e = buf[t] - v; bbase[t] = e; bcur[t] = e; }
    if (t == nb) bbase[nb] = buf[nb - 1];
    if (t == 0) rowptr[n] = etot;
}

__global__ __launch_bounds__(256) void k_bpart(const int* __restrict__ srcA,
                                               const int* __restrict__ dstA,
                                               int* __restrict__ bcur,
                                               unsigned* __restrict__ ebuf,
                                               int nE, int n) {
    __shared__ int cnt[512];
    __shared__ int run[512];
    int t = threadIdx.x;
    cnt[t] = 0; cnt[t + 256] = 0;
    __syncthreads();
    int tot = nE + n;
    int chunk = (tot + gridDim.x - 1) / gridDim.x;
    int c0 = blockIdx.x * chunk;
    int c1 = min(c0 + chunk, tot);
    for (int i = c0 + t; i < c1; i += 256) {
        int d = (i < nE) ? dstA[i] : (i - nE);
        atomicAdd(&cnt[d >> BSHIFT], 1);
    }
    __syncthreads();
    int c = cnt[t];
    if (c) run[t] = atomicAdd(&bcur[t], c);
    int c2 = cnt[t + 256];
    if (c2) run[t + 256] = atomicAdd(&bcur[t + 256], c2);
    __syncthreads();
    cnt[t] = 0; cnt[t + 256] = 0;
    __syncthreads();
    for (int i = c0 + t; i < c1; i += 256) {
        int s, d;
        if (i < nE) { s = srcA[i]; d = dstA[i]; }
        else        { s = d = i - nE; }
        int b = d >> BSHIFT;
        int pos = run[b] + atomicAdd(&cnt[b], 1);
        ebuf[pos] = ((unsigned)s << BSHIFT) | (unsigned)(d & (BSIZE - 1));
    }
}

__global__ __launch_bounds__(512) void k_bfill(const unsigned* __restrict__ ebuf,
                                               const int* __restrict__ bbase,
                                               int* __restrict__ rowptr,
                                               int* __restrict__ csr,
                                               int n, int nb) {
    int b = blockIdx.x;
    int lo = bbase[b], hi = bbase[b + 1];
    int cnt = hi - lo;
    int node0 = b << BSHIFT;
    __shared__ int deg[512];
    __shared__ int sbuf[512];
    __shared__ int cur[512];
    __shared__ unsigned stage[STAGE_CAP];
    int t = threadIdx.x;
    deg[t] = 0;
    __syncthreads();
    bool st = (cnt <= STAGE_CAP);
    for (int i = lo + t; i < hi; i += 512) {
        unsigned e = ebuf[i];
        if (st) stage[i - lo] = e;
        atomicAdd(&deg[e & (BSIZE - 1)], 1);
    }
    __syncthreads();
    int d = deg[t];
    sbuf[t] = d;
    __syncthreads();
    for (int off = 1; off < 512; off <<= 1) {
        int x = (t >= off) ? sbuf[t - off] : 0;
        __syncthreads();
        sbuf[t] += x;
        __syncthreads();
    }
    int excl = sbuf[t] - d;
    if (node0 + t < n) rowptr[node0 + t] = lo + excl;
    cur[t] = excl;
    __syncthreads();
    for (int i = lo + t; i < hi; i += 512) {
        unsigned e = st ? stage[i - lo] : ebuf[i];
        int pos = atomicAdd(&cur[e & (BSIZE - 1)], 1);
        csr[lo + pos] = (int)(e >> BSHIFT);
    }
}

// ---------------- GAT linear: xl(fp16) = h@Wl+bl, xr(fp32) = h@Wr+br --------
// Panel 0 -> Wl/xl(fp16), panel 1 -> Wr/xr(f32). 16KB weight LDS, 4 rows x
// 4 cols per thread, rows direct from global, k4 loop fully unrolled.

__global__ __launch_bounds__(256) void k_gat_gemm(
        const float* __restrict__ hin,
        const float* __restrict__ Wl, const float* __restrict__ bl,
        const float* __restrict__ Wr, const float* __restrict__ br,
        __half* __restrict__ xl, float* __restrict__ xr, int n) {
    __shared__ float sW[64 * 64];    // 16KB
    int tid = threadIdx.x;
    int bpp = gridDim.x >> 1;
    int panel = (blockIdx.x >= bpp) ? 1 : 0;
    int b2 = blockIdx.x - panel * bpp;
    const float* Wsrc = panel ? Wr : Wl;
    const float* bsrc = panel ? br : bl;
    for (int i = tid; i < 64 * 64; i += 256) sW[i] = Wsrc[i];
    __syncthreads();
    int cg = tid & 15, rt = tid >> 4;    // 16 col-groups x 16 row-groups
    int c0 = cg * 4;
    float4 bias4 = *reinterpret_cast<const float4*>(bsrc + c0);
    const float4* sW4 = reinterpret_cast<const float4*>(sW);
    for (int r0 = b2 * 64; r0 < n; r0 += bpp * 64) {
        int rb = r0 + rt * 4;
        const float4* rp[4];
        #pragma unroll
        for (int i = 0; i < 4; ++i) {
            int rc = rb + i; if (rc > n - 1) rc = n - 1;
            rp[i] = reinterpret_cast<const float4*>(hin + (size_t)rc * 64);
        }
        float4 acc[4];
        #pragma unroll
        for (int i = 0; i < 4; ++i) acc[i] = bias4;
        #pragma unroll
        for (int k4 = 0; k4 < 16; ++k4) {
            float4 w0 = sW4[(k4 * 4 + 0) * 16 + cg];
            float4 w1 = sW4[(k4 * 4 + 1) * 16 + cg];
            float4 w2 = sW4[(k4 * 4 + 2) * 16 + cg];
            float4 w3 = sW4[(k4 * 4 + 3) * 16 + cg];
            #pragma unroll
            for (int i = 0; i < 4; ++i) {
                float4 h4 = rp[i][k4];
                acc[i].x = fmaf(h4.x, w0.x, acc[i].x); acc[i].y = fmaf(h4.x, w0.y, acc[i].y);
                acc[i].z = fmaf(h4.x, w0.z, acc[i].z); acc[i].w = fmaf(h4.x, w0.w, acc[i].w);
                acc[i].x = fmaf(h4.y, w1.x, acc[i].x); acc[i].y = fmaf(h4.y, w1.y, acc[i].y);
                acc[i].z = fmaf(h4.y, w1.z, acc[i].z); acc[i].w = fmaf(h4.y, w1.w, acc[i].w);
                acc[i].x = fmaf(h4.z, w2.x, acc[i].x); acc[i].y = fmaf(h4.z, w2.y, acc[i].y);
                acc[i].z = fmaf(h4.z, w2.z, acc[i].z); acc[i].w = fmaf(h4.z, w2.w, acc[i].w);
                acc[i].x = fmaf(h4.w, w3.x, acc[i].x); acc[i].y = fmaf(h4.w, w3.y, acc[i].y);
                acc[i].z = fmaf(h4.w, w3.z, acc[i].z); acc[i].w = fmaf(h4.w, w3.w, acc[i].w);
            }
        }
        if (panel == 0) {
            #pragma unroll
            for (int i = 0; i < 4; ++i) {
                int r = rb + i;
                if (r < n) {
                    union { __half2 h2[2]; uint2 u; } pk;
                    pk.h2[0] = __floats2half2_rn(acc[i].x, acc[i].y);
                    pk.h2[1] = __floats2half2_rn(acc[i].z, acc[i].w);
                    *reinterpret_cast<uint2*>(xl + (size_t)r * 64 + c0) = pk.u;
                }
            }
        } else {
            #pragma unroll
            for (int i = 0; i < 4; ++i) {
                int r = rb + i;
                if (r < n)
                    *reinterpret_cast<float4*>(xr + (size_t)r * 64 + c0) = acc[i];
            }
        }
    }
}

// ---------------- GAT edge aggregation (group-parallel online softmax) ------
// unchanged (replay-proven). wave = 1 node; 4 groups of 16 lanes each own an
// edge; lane owns 4 channels.

__global__ __launch_bounds__(256) void k_gat_edge(
        const __half* __restrict__ xl, const float* __restrict__ xr,
        const int* __restrict__ rowptr, const int* __restrict__ csr_src,
        const float* __restrict__ att, const float* __restrict__ bias,
        float* __restrict__ hout, int n, int do_relu) {
    int node = blockIdx.x * 4 + (threadIdx.x >> 6);
    if (node >= n) return;
    int lane = threadIdx.x & 63;
    int grp = lane >> 4, sub = lane & 15;
    int c0 = sub << 2;
    float4 attv = *reinterpret_cast<const float4*>(att + c0);
    float4 xrv  = *reinterpret_cast<const float4*>(xr + (size_t)node * 64 + c0);
    int beg = rowptr[node], end = rowptr[node + 1];
    float m = -INFINITY, s = 0.f;
    float acc0 = 0.f, acc1 = 0.f, acc2 = 0.f, acc3 = 0.f;
    for (int k0 = beg; k0 < end; k0 += 4) {
        int kk = k0 + grp;
        int idx = csr_src[kk < end ? kk : end - 1];
        uint2 raw = *reinterpret_cast<const uint2*>(xl + ((size_t)idx << 6) + c0);
        float2 f01 = __half22float2(*reinterpret_cast<__half2*>(&raw.x));
        float2 f23 = __half22float2(*reinterpret_cast<__half2*>(&raw.y));
        float v0 = f01.x, v1 = f01.y, v2 = f23.x, v3 = f23.y;
        float t0 = v0 + xrv.x; t0 = (t0 > 0.f) ? t0 : 0.2f * t0;
        float t1 = v1 + xrv.y; t1 = (t1 > 0.f) ? t1 : 0.2f * t1;
        float t2 = v2 + xrv.z; t2 = (t2 > 0.f) ? t2 : 0.2f * t2;
        float t3 = v3 + xrv.w; t3 = (t3 > 0.f) ? t3 : 0.2f * t3;
        float p = fmaf(t3, attv.w, fmaf(t2, attv.z, fmaf(t1, attv.y, t0 * attv.x)));
        p += __shfl_xor(p, 1);
        p += __shfl_xor(p, 2);
        p += __shfl_xor(p, 4);
        p += __shfl_xor(p, 8);
        float p0 = __shfl(p, sub);
        float p1 = __shfl(p, 16 + sub);
        float p2 = __shfl(p, 32 + sub);
        float p3 = __shfl(p, 48 + sub);
        int rem = end - k0;
        if (rem < 4) {
            if (rem <= 1) p1 = -INFINITY;
            if (rem <= 2) p2 = -INFINITY;
            if (rem <= 3) p3 = -INFINITY;
        }
        float mx = fmaxf(fmaxf(fmaxf(p0, p1), fmaxf(p2, p3)), m);
        float sc = __expf(m - mx);
        float w0 = __expf(p0 - mx), w1 = __expf(p1 - mx);
        float w2 = __expf(p2 - mx), w3 = __expf(p3 - mx);
        float wm = (grp < 2) ? ((grp == 0) ? w0 : w1) : ((grp == 2) ? w2 : w3);
        s = s * sc + ((w0 + w1) + (w2 + w3));
        acc0 = fmaf(wm, v0, acc0 * sc);
        acc1 = fmaf(wm, v1, acc1 * sc);
        acc2 = fmaf(wm, v2, acc2 * sc);
        acc3 = fmaf(wm, v3, acc3 * sc);
        m = mx;
    }
    acc0 += __shfl_xor(acc0, 16); acc0 += __shfl_xor(acc0, 32);
    acc1 += __shfl_xor(acc1, 16); acc1 += __shfl_xor(acc1, 32);
    acc2 += __shfl_xor(acc2, 16); acc2 += __shfl_xor(acc2, 32);
    acc3 += __shfl_xor(acc3, 16); acc3 += __shfl_xor(acc3, 32);
    float inv = 1.0f / s;
    float4 bv = *reinterpret_cast<const float4*>(bias + c0);
    float o0 = fmaf(acc0, inv, bv.x);
    float o1 = fmaf(acc1, inv, bv.y);
    float o2 = fmaf(acc2, inv, bv.z);
    float o3 = fmaf(acc3, inv, bv.w);
    if (do_relu) {
        o0 = fmaxf(o0, 0.f); o1 = fmaxf(o1, 0.f);
        o2 = fmaxf(o2, 0.f); o3 = fmaxf(o3, 0.f);
    }
    if (grp == 0) {
        *reinterpret_cast<float4*>(hout + (size_t)node * 64 + c0) =
            make_float4(o0, o1, o2, o3);
    }
}

// ---------------- MLP GEMM: full weight panel in LDS, 4 rows x 4 cols -------
// k4 loop fully unrolled (DIN=64) / unroll-8 (DIN=128) for load ILP; BN coeff
// fetch hoisted per-k4; stats scratch aliases dead sW.

#define MLP_BODY(k4)                                                           \
    {                                                                          \
        float4 w0 = sW4[((k4) * 4 + 0) * CG + cg];                             \
        float4 w1 = sW4[((k4) * 4 + 1) * CG + cg];                             \
        float4 w2 = sW4[((k4) * 4 + 2) * CG + cg];                             \
        float4 w3 = sW4[((k4) * 4 + 3) * CG + cg];                             \
        float4 a4 = make_float4(0.f, 0.f, 0.f, 0.f);                           \
        float4 b4n = make_float4(0.f, 0.f, 0.f, 0.f);                          \
        if (BN_IN) {                                                           \
            a4  = *reinterpret_cast<const float4*>(sA + (k4) * 4);             \
            b4n = *reinterpret_cast<const float4*>(sB + (k4) * 4);             \
        }                                                                      \
        _Pragma("unroll")                                                      \
        for (int i = 0; i < 4; ++i) {                                          \
            float4 h4 = rp[i][(k4)];                                           \
            if (BN_IN) {                                                       \
                h4.x = fmaxf(fmaf(h4.x, a4.x, b4n.x), 0.f);                    \
                h4.y = fmaxf(fmaf(h4.y, a4.y, b4n.y), 0.f);                    \
                h4.z = fmaxf(fmaf(h4.z, a4.z, b4n.z), 0.f);                    \
                h4.w = fmaxf(fmaf(h4.w, a4.w, b4n.w), 0.f);                    \
            }                                                                  \
            acc[i].x = fmaf(h4.x, w0.x, acc[i].x); acc[i].y = fmaf(h4.x, w0.y, acc[i].y); \
            acc[i].z = fmaf(h4.x, w0.z, acc[i].z); acc[i].w = fmaf(h4.x, w0.w, acc[i].w); \
            acc[i].x = fmaf(h4.y, w1.x, acc[i].x); acc[i].y = fmaf(h4.y, w1.y, acc[i].y); \
            acc[i].z = fmaf(h4.y, w1.z, acc[i].z); acc[i].w = fmaf(h4.y, w1.w, acc[i].w); \
            acc[i].x = fmaf(h4.z, w2.x, acc[i].x); acc[i].y = fmaf(h4.z, w2.y, acc[i].y); \
            acc[i].z = fmaf(h4.z, w2.z, acc[i].z); acc[i].w = fmaf(h4.z, w2.w, acc[i].w); \
            acc[i].x = fmaf(h4.w, w3.x, acc[i].x); acc[i].y = fmaf(h4.w, w3.y, acc[i].y); \
            acc[i].z = fmaf(h4.w, w3.z, acc[i].z); acc[i].w = fmaf(h4.w, w3.w, acc[i].w); \
        }                                                                      \
    }

template <int DIN, int DOUT, int BN_IN>
__global__ __launch_bounds__(256) void k_mlp_gemm(
        const float* __restrict__ hin, const float* __restrict__ W,
        const float* __restrict__ bias, float* __restrict__ z,
        float* __restrict__ stat_sum, float* __restrict__ stat_sq,
        const float* __restrict__ muI, const float* __restrict__ ivI,
        const float* __restrict__ gI, const float* __restrict__ beI,
        int n) {
    constexpr int CG   = DOUT / 4;    // col groups: 32 (L0) or 16 (L1)
    constexpr int RG   = 256 / CG;    // row groups: 8 or 16
    constexpr int ROWS = RG * 4;      // rows per block-iter: 32 or 64
    constexpr int ABN  = BN_IN ? DIN : 4;
    __shared__ float sW[DIN * DOUT];  // 32KB
    __shared__ float sA[ABN], sB[ABN];
    int tid = threadIdx.x;
    for (int i = tid; i < DIN * DOUT; i += 256) sW[i] = W[i];
    if (BN_IN && tid < DIN) {
        float a = ivI[tid] * gI[tid];
        sA[tid] = a;
        sB[tid] = beI[tid] - muI[tid] * a;
    }
    __syncthreads();
    int cg = tid % CG, rt = tid / CG;
    int c0 = cg * 4;
    float4 bias4 = *reinterpret_cast<const float4*>(bias + c0);
    const float4* sW4 = reinterpret_cast<const float4*>(sW);
    float4 ls = make_float4(0.f, 0.f, 0.f, 0.f);
    float4 lq = make_float4(0.f, 0.f, 0.f, 0.f);
    for (int r0 = blockIdx.x * ROWS; r0 < n; r0 += gridDim.x * ROWS) {
        int rb = r0 + rt * 4;
        const float4* rp[4];
        #pragma unroll
        for (int i = 0; i < 4; ++i) {
            int rc = rb + i; if (rc > n - 1) rc = n - 1;
            rp[i] = reinterpret_cast<const float4*>(hin + (size_t)rc * DIN);
        }
        float4 acc[4];
        #pragma unroll
        for (int i = 0; i < 4; ++i) acc[i] = bias4;
        if constexpr (DIN == 64) {
            #pragma unroll
            for (int k4 = 0; k4 < 16; ++k4) MLP_BODY(k4)
        } else {
            #pragma unroll 8
            for (int k4 = 0; k4 < DIN / 4; ++k4) MLP_BODY(k4)
        }
        #pragma unroll
        for (int i = 0; i < 4; ++i) {
            int r = rb + i;
            if (r < n) {
                *reinterpret_cast<float4*>(z + (size_t)r * DOUT + c0) = acc[i];
                ls.x += acc[i].x; ls.y += acc[i].y;
                ls.z += acc[i].z; ls.w += acc[i].w;
                lq.x = fmaf(acc[i].x, acc[i].x, lq.x);
                lq.y = fmaf(acc[i].y, acc[i].y, lq.y);
                lq.z = fmaf(acc[i].z, acc[i].z, lq.z);
                lq.w = fmaf(acc[i].w, acc[i].w, lq.w);
            }
        }
    }
    // BN stats block-reduce; scratch aliases sW (dead after this barrier)
    __syncthreads();
    float4* red4 = reinterpret_cast<float4*>(sW);
    red4[tid] = ls;
    __syncthreads();
    if (rt == 0) {
        float4 t = red4[cg];
        for (int g2 = 1; g2 < RG; ++g2) {
            float4 u = red4[g2 * CG + cg];
            t.x += u.x; t.y += u.y; t.z += u.z; t.w += u.w;
        }
        atomicAdd(&stat_sum[c0],     t.x); atomicAdd(&stat_sum[c0 + 1], t.y);
        atomicAdd(&stat_sum[c0 + 2], t.z); atomicAdd(&stat_sum[c0 + 3], t.w);
    }
    __syncthreads();
    red4[tid] = lq;
    __syncthreads();
    if (rt == 0) {
        float4 t = red4[cg];
        for (int g2 = 1; g2 < RG; ++g2) {
            float4 u = red4[g2 * CG + cg];
            t.x += u.x; t.y += u.y; t.z += u.z; t.w += u.w;
        }
        atomicAdd(&stat_sq[c0],     t.x); atomicAdd(&stat_sq[c0 + 1], t.y);
        atomicAdd(&stat_sq[c0 + 2], t.z); atomicAdd(&stat_sq[c0 + 3], t.w);
    }
}

__global__ void k_bn_fin(const float* __restrict__ ssum, const float* __restrict__ ssq,
                         float* __restrict__ mu, float* __restrict__ inv,
                         int n, int dout) {
    int c = threadIdx.x;
    if (c >= dout) return;
    float m = ssum[c] / (float)n;
    float v = ssq[c] / (float)n - m * m;
    mu[c]  = m;
    inv[c] = rsqrtf(fmaxf(v, 0.f) + 1e-5f);
}

// ---------------- fused BN1+ReLU + final linear (64->1) + segmented mean-pool -

__global__ __launch_bounds__(256) void k_pool_seg(
        const float* __restrict__ h2, const float* __restrict__ w2,
        const float* __restrict__ b2, const int* __restrict__ batch,
        const float* __restrict__ mu1, const float* __restrict__ iv1,
        const float* __restrict__ g1, const float* __restrict__ be1,
        float* __restrict__ out, int n) {
    int g = blockIdx.x;
    int tid = threadIdx.x;
    int lo = 0, hi = n;
    while (lo < hi) { int mid = (lo + hi) >> 1; if (batch[mid] < g) lo = mid + 1; else hi = mid; }
    int start = lo;
    hi = n;
    while (lo < hi) { int mid = (lo + hi) >> 1; if (batch[mid] < g + 1) lo = mid + 1; else hi = mid; }
    int end = lo;
    int cnt = end - start;

    int c = (tid << 2) & 63;
    float A0 = iv1[c] * g1[c],         B0 = be1[c] - mu1[c] * A0;
    float A1 = iv1[c + 1] * g1[c + 1], B1 = be1[c + 1] - mu1[c + 1] * A1;
    float A2 = iv1[c + 2] * g1[c + 2], B2 = be1[c + 2] - mu1[c + 2] * A2;
    float A3 = iv1[c + 3] * g1[c + 3], B3 = be1[c + 3] - mu1[c + 3] * A3;
    float wa = w2[c], wb = w2[c + 1], wc = w2[c + 2], wd = w2[c + 3];
    const float4* b4 = reinterpret_cast<const float4*>(h2 + (size_t)start * 64);
    long total4 = (long)cnt * 16;
    float acc = 0.f;
    for (long i = tid; i < total4; i += 256) {
        float4 v = b4[i];
        acc = fmaf(fmaxf(fmaf(v.x, A0, B0), 0.f), wa, acc);
        acc = fmaf(fmaxf(fmaf(v.y, A1, B1), 0.f), wb, acc);
        acc = fmaf(fmaxf(fmaf(v.z, A2, B2), 0.f), wc, acc);
        acc = fmaf(fmaxf(fmaf(v.w, A3, B3), 0.f), wd, acc);
    }
    __shared__ float red[256];
    red[tid] = acc; __syncthreads();
    for (int off = 128; off; off >>= 1) {
        if (tid < off) red[tid] += red[tid + off];
        __syncthreads();
    }
    if (tid == 0) out[g] = (cnt > 0) ? red[0] / (float)cnt + b2[0] : 0.f;
}

// ---------------------------------------------------------------------------

extern "C" void kernel_launch(void* const* d_in, const int* in_sizes, int n_in,
                              void* d_out, int out_size, void* d_ws, size_t ws_size,
                              hipStream_t stream) {
    const float* x     = (const float*)d_in[0];
    const int*   ei    = (const int*)d_in[1];
    const int*   batch = (const int*)d_in[2];

    const int N = in_sizes[0] / 64;
    const int E = in_sizes[1] / 2;
    const int G = out_size;
    const int Etot = E + N;
    const int NB = (N + BSIZE - 1) >> BSHIFT;

    const int* srcA = ei;
    const int* dstA = ei + E;

    const float* Wl[3]; const float* bl[3]; const float* Wr[3];
    const float* br[3]; const float* att[3]; const float* bb[3];
    for (int l = 0; l < 3; ++l) {
        int base = 3 + 6 * l;
        Wl[l]  = (const float*)d_in[base + 0];
        bl[l]  = (const float*)d_in[base + 1];
        Wr[l]  = (const float*)d_in[base + 2];
        br[l]  = (const float*)d_in[base + 3];
        att[l] = (const float*)d_in[base + 4];
        bb[l]  = (const float*)d_in[base + 5];
    }
    const float* mW0 = (const float*)d_in[21];
    const float* mb0 = (const float*)d_in[22];
    const float* g0  = (const float*)d_in[23];
    const float* be0 = (const float*)d_in[24];
    const float* mW1 = (const float*)d_in[25];
    const float* mb1 = (const float*)d_in[26];
    const float* g1  = (const float*)d_in[27];
    const float* be1 = (const float*)d_in[28];
    const float* mW2 = (const float*)d_in[29];
    const float* mb2 = (const float*)d_in[30];

    // ---- workspace carve ----
    char* w = (char*)d_ws;
    auto alloc = [&](size_t bytes) -> void* {
        void* p = (void*)w;
        w += (bytes + 255) & ~(size_t)255;
        return p;
    };
    int*    rowptr = (int*)alloc((size_t)(N + 1) * 4);
    int*    csr    = (int*)alloc((size_t)Etot * 4);
    int*    bcnt   = (int*)alloc(512 * 4);
    int*    bbase  = (int*)alloc(520 * 4);
    int*    bcur   = (int*)alloc(512 * 4);
    // xl(half,12.8MB) + xr(f32,25.6MB) + zext(12.8MB) contiguous; z spans them
    __half* xl     = (__half*)alloc((size_t)N * 64 * 2);
    float*  xr     = (float*)alloc((size_t)N * 64 * 4);
    float*  zext   = (float*)alloc((size_t)N * 32 * 4);
    float*  h      = (float*)alloc((size_t)N * 64 * 4);
    float*  stats  = (float*)alloc(8 * 128 * 4);
    float*  z      = (float*)xl;          // [N,128] fp32 spans xl+xr+zext
    unsigned* ebuf = (unsigned*)h;        // dead before h is live
    (void)zext;

    float* sum0 = stats;        float* sq0 = stats + 128;
    float* mu0  = stats + 256;  float* iv0 = stats + 384;
    float* sum1 = stats + 512;  float* sq1 = stats + 640;
    float* mu1  = stats + 768;  float* iv1 = stats + 896;

    // ---- bucketed CSR build ----
    hipMemsetAsync(bcnt, 0, 512 * 4, stream);
    k_bcount<<<256, 256, 0, stream>>>(dstA, bcnt, E, N);
    k_bscan<<<1, 512, 0, stream>>>(bcnt, bbase, bcur, rowptr, NB, N, Etot);
    k_bpart<<<256, 256, 0, stream>>>(srcA, dstA, bcur, ebuf, E, N);
    k_bfill<<<NB, 512, 0, stream>>>(ebuf, bbase, rowptr, csr, N, NB);

    // ---- 3x GATv2 ----
    int nodeBlocks = (N + 3) / 4;
    int bppG = (N + 63) / 64;            // single-pass per panel
    const float* hin = x;
    for (int l = 0; l < 3; ++l) {
        k_gat_gemm<<<2 * bppG, 256, 0, stream>>>(hin, Wl[l], bl[l], Wr[l], br[l],
                                                 xl, xr, N);
        k_gat_edge<<<nodeBlocks, 256, 0, stream>>>(xl, xr, rowptr, csr,
                                                   att[l], bb[l], h, N,
                                                   (l < 2) ? 1 : 0);
        hin = h;
    }

    // ---- MLP layer 0: 64 -> 128 (stats for BN0); single-pass grid ----
    hipMemsetAsync(sum0, 0, 2 * 128 * 4, stream);
    k_mlp_gemm<64, 128, 0><<<(N + 31) / 32, 256, 0, stream>>>(
        h, mW0, mb0, z, sum0, sq0, nullptr, nullptr, nullptr, nullptr, N);
    k_bn_fin<<<1, 128, 0, stream>>>(sum0, sq0, mu0, iv0, N, 128);

    // ---- MLP layer 1: 128 -> 64, BN0+ReLU fused; single-pass grid ----
    hipMemsetAsync(sum1, 0, 2 * 128 * 4, stream);
    k_mlp_gemm<128, 64, 1><<<(N + 63) / 64, 256, 0, stream>>>(
        z, mW1, mb1, h, sum1, sq1, mu0, iv0, g0, be0, N);
    k_bn_fin<<<1, 64, 0, stream>>>(sum1, sq1, mu1, iv1, N, 64);

    // ---- fused BN1+ReLU + final linear + segmented mean pool ----
    k_pool_seg<<<G, 256, 0, stream>>>(h, mW2, mb2, batch, mu1, iv1, g1, be1,
                                      (float*)d_out, N);
}

// Round 12
// 597.801 us; speedup vs baseline: 3.1368x; 3.1368x over previous
//
#include <hip/hip_runtime.h>
#include <hip/hip_bf16.h>
#include <hip/hip_fp16.h>
#include <math.h>

// ---------------------------------------------------------------------------
// MolGAT: 3x GATv2 (heads=1, D=64) + MLP(64->128->64->1, BN train-stats) +
// global mean pool over G=256 graphs.
// R11: reassembled from best-measured, replay-proven components after R10's
// full-unroll spill disaster (VGPR 256, 569MB scratch writes, 386us/gemm):
//   - k_mlp_gemm: R5 verbatim (register weights, 16-row LDS stage; 100us).
//   - k_gat_gemm: R9 paneled unroll-2 (16KB LDS, VGPR 52; ~40us).
//   - k_gat_edge: R5 group-parallel + 2-stage prefetch (idx 2-ahead, data
//     1-ahead, clamped/branch-free) to hide the ~300-450cy gather latency
//     (was 65us at 1TB/s effective with FETCH=101MB).
// ---------------------------------------------------------------------------

#define BSHIFT 9
#define BSIZE  512   // nodes per bucket
#define STAGE_CAP 24576

// ---------------- bucketed CSR build (unchanged, replay-proven) ----------------

__global__ __launch_bounds__(256) void k_bcount(const int* __restrict__ dstA,
                                                int* __restrict__ bcnt,
                                                int nE, int n) {
    __shared__ int h[512];
    int t = threadIdx.x;
    h[t] = 0; h[t + 256] = 0;
    __syncthreads();
    int tot = nE + n;
    for (int i = blockIdx.x * 256 + t; i < tot; i += gridDim.x * 256) {
        int d = (i < nE) ? dstA[i] : (i - nE);   // self loops appended
        atomicAdd(&h[d >> BSHIFT], 1);
    }
    __syncthreads();
    if (h[t])       atomicAdd(&bcnt[t], h[t]);
    if (h[t + 256]) atomicAdd(&bcnt[t + 256], h[t + 256]);
}

__global__ __launch_bounds__(512) void k_bscan(const int* __restrict__ bcnt,
                                               int* __restrict__ bbase,
                                               int* __restrict__ bcur,
                                               int* __restrict__ rowptr,
                                               int nb, int n, int etot) {
    __shared__ int buf[512];
    int t = threadIdx.x;
    int v = (t < nb) ? bcnt[t] : 0;
    buf[t] = v;
    __syncthreads();
    for (int off = 1; off < 512; off <<= 1) {
        int x = (t >= off) ? buf[t - off] : 0;
        __syncthreads();
        buf[t] += x;
        __syncthreads();
    }
    if (t < nb) { int e = buf[t] - v; bbase[t] = e; bcur[t] = e; }
    if (t == nb) bbase[nb] = buf[nb - 1];
    if (t == 0) rowptr[n] = etot;
}

__global__ __launch_bounds__(256) void k_bpart(const int* __restrict__ srcA,
                                               const int* __restrict__ dstA,
                                               int* __restrict__ bcur,
                                               unsigned* __restrict__ ebuf,
                                               int nE, int n) {
    __shared__ int cnt[512];
    __shared__ int run[512];
    int t = threadIdx.x;
    cnt[t] = 0; cnt[t + 256] = 0;
    __syncthreads();
    int tot = nE + n;
    int chunk = (tot + gridDim.x - 1) / gridDim.x;
    int c0 = blockIdx.x * chunk;
    int c1 = min(c0 + chunk, tot);
    for (int i = c0 + t; i < c1; i += 256) {
        int d = (i < nE) ? dstA[i] : (i - nE);
        atomicAdd(&cnt[d >> BSHIFT], 1);
    }
    __syncthreads();
    int c = cnt[t];
    if (c) run[t] = atomicAdd(&bcur[t], c);
    int c2 = cnt[t + 256];
    if (c2) run[t + 256] = atomicAdd(&bcur[t + 256], c2);
    __syncthreads();
    cnt[t] = 0; cnt[t + 256] = 0;
    __syncthreads();
    for (int i = c0 + t; i < c1; i += 256) {
        int s, d;
        if (i < nE) { s = srcA[i]; d = dstA[i]; }
        else        { s = d = i - nE; }
        int b = d >> BSHIFT;
        int pos = run[b] + atomicAdd(&cnt[b], 1);
        ebuf[pos] = ((unsigned)s << BSHIFT) | (unsigned)(d & (BSIZE - 1));
    }
}

__global__ __launch_bounds__(512) void k_bfill(const unsigned* __restrict__ ebuf,
                                               const int* __restrict__ bbase,
                                               int* __restrict__ rowptr,
                                               int* __restrict__ csr,
                                               int n, int nb) {
    int b = blockIdx.x;
    int lo = bbase[b], hi = bbase[b + 1];
    int cnt = hi - lo;
    int node0 = b << BSHIFT;
    __shared__ int deg[512];
    __shared__ int sbuf[512];
    __shared__ int cur[512];
    __shared__ unsigned stage[STAGE_CAP];
    int t = threadIdx.x;
    deg[t] = 0;
    __syncthreads();
    bool st = (cnt <= STAGE_CAP);
    for (int i = lo + t; i < hi; i += 512) {
        unsigned e = ebuf[i];
        if (st) stage[i - lo] = e;
        atomicAdd(&deg[e & (BSIZE - 1)], 1);
    }
    __syncthreads();
    int d = deg[t];
    sbuf[t] = d;
    __syncthreads();
    for (int off = 1; off < 512; off <<= 1) {
        int x = (t >= off) ? sbuf[t - off] : 0;
        __syncthreads();
        sbuf[t] += x;
        __syncthreads();
    }
    int excl = sbuf[t] - d;
    if (node0 + t < n) rowptr[node0 + t] = lo + excl;
    cur[t] = excl;
    __syncthreads();
    for (int i = lo + t; i < hi; i += 512) {
        unsigned e = st ? stage[i - lo] : ebuf[i];
        int pos = atomicAdd(&cur[e & (BSIZE - 1)], 1);
        csr[lo + pos] = (int)(e >> BSHIFT);
    }
}

// ---------------- GAT linear (R9 paneled, unroll 2; replay-proven) ----------
// Panel 0 -> Wl/xl(fp16), panel 1 -> Wr/xr(f32). 16KB weight LDS, 4 rows x
// 4 cols per thread, rows direct from global.

__global__ __launch_bounds__(256) void k_gat_gemm(
        const float* __restrict__ hin,
        const float* __restrict__ Wl, const float* __restrict__ bl,
        const float* __restrict__ Wr, const float* __restrict__ br,
        __half* __restrict__ xl, float* __restrict__ xr, int n) {
    __shared__ float sW[64 * 64];    // 16KB
    int tid = threadIdx.x;
    int bpp = gridDim.x >> 1;
    int panel = (blockIdx.x >= bpp) ? 1 : 0;
    int b2 = blockIdx.x - panel * bpp;
    const float* Wsrc = panel ? Wr : Wl;
    const float* bsrc = panel ? br : bl;
    for (int i = tid; i < 64 * 64; i += 256) sW[i] = Wsrc[i];
    __syncthreads();
    int cg = tid & 15, rt = tid >> 4;    // 16 col-groups x 16 row-groups
    int c0 = cg * 4;
    float4 bias4 = *reinterpret_cast<const float4*>(bsrc + c0);
    const float4* sW4 = reinterpret_cast<const float4*>(sW);
    for (int r0 = b2 * 64; r0 < n; r0 += bpp * 64) {
        int rb = r0 + rt * 4;
        const float4* rp[4];
        #pragma unroll
        for (int i = 0; i < 4; ++i) {
            int rc = rb + i; if (rc > n - 1) rc = n - 1;
            rp[i] = reinterpret_cast<const float4*>(hin + (size_t)rc * 64);
        }
        float4 acc[4];
        #pragma unroll
        for (int i = 0; i < 4; ++i) acc[i] = bias4;
        #pragma unroll 2
        for (int k4 = 0; k4 < 16; ++k4) {
            float4 w0 = sW4[(k4 * 4 + 0) * 16 + cg];
            float4 w1 = sW4[(k4 * 4 + 1) * 16 + cg];
            float4 w2 = sW4[(k4 * 4 + 2) * 16 + cg];
            float4 w3 = sW4[(k4 * 4 + 3) * 16 + cg];
            #pragma unroll
            for (int i = 0; i < 4; ++i) {
                float4 h4 = rp[i][k4];
                acc[i].x = fmaf(h4.x, w0.x, acc[i].x); acc[i].y = fmaf(h4.x, w0.y, acc[i].y);
                acc[i].z = fmaf(h4.x, w0.z, acc[i].z); acc[i].w = fmaf(h4.x, w0.w, acc[i].w);
                acc[i].x = fmaf(h4.y, w1.x, acc[i].x); acc[i].y = fmaf(h4.y, w1.y, acc[i].y);
                acc[i].z = fmaf(h4.y, w1.z, acc[i].z); acc[i].w = fmaf(h4.y, w1.w, acc[i].w);
                acc[i].x = fmaf(h4.z, w2.x, acc[i].x); acc[i].y = fmaf(h4.z, w2.y, acc[i].y);
                acc[i].z = fmaf(h4.z, w2.z, acc[i].z); acc[i].w = fmaf(h4.z, w2.w, acc[i].w);
                acc[i].x = fmaf(h4.w, w3.x, acc[i].x); acc[i].y = fmaf(h4.w, w3.y, acc[i].y);
                acc[i].z = fmaf(h4.w, w3.z, acc[i].z); acc[i].w = fmaf(h4.w, w3.w, acc[i].w);
            }
        }
        if (panel == 0) {
            #pragma unroll
            for (int i = 0; i < 4; ++i) {
                int r = rb + i;
                if (r < n) {
                    union { __half2 h2[2]; uint2 u; } pk;
                    pk.h2[0] = __floats2half2_rn(acc[i].x, acc[i].y);
                    pk.h2[1] = __floats2half2_rn(acc[i].z, acc[i].w);
                    *reinterpret_cast<uint2*>(xl + (size_t)r * 64 + c0) = pk.u;
                }
            }
        } else {
            #pragma unroll
            for (int i = 0; i < 4; ++i) {
                int r = rb + i;
                if (r < n)
                    *reinterpret_cast<float4*>(xr + (size_t)r * 64 + c0) = acc[i];
            }
        }
    }
}

// ---------------- GAT edge aggregation (group-parallel + 2-stage prefetch) --
// wave = 1 node; 4 groups of 16 lanes each own an edge; lane owns 4 channels.
// Prefetch: csr index 2 iterations ahead, xl vector 1 ahead (clamped).

__global__ __launch_bounds__(256) void k_gat_edge(
        const __half* __restrict__ xl, const float* __restrict__ xr,
        const int* __restrict__ rowptr, const int* __restrict__ csr_src,
        const float* __restrict__ att, const float* __restrict__ bias,
        float* __restrict__ hout, int n, int do_relu) {
    int node = blockIdx.x * 4 + (threadIdx.x >> 6);
    if (node >= n) return;
    int lane = threadIdx.x & 63;
    int grp = lane >> 4, sub = lane & 15;
    int c0 = sub << 2;
    float4 attv = *reinterpret_cast<const float4*>(att + c0);
    float4 xrv  = *reinterpret_cast<const float4*>(xr + (size_t)node * 64 + c0);
    int beg = rowptr[node], end = rowptr[node + 1];
    int e1 = end - 1;
    float m = -INFINITY, s = 0.f;
    float acc0 = 0.f, acc1 = 0.f, acc2 = 0.f, acc3 = 0.f;
    // pipeline prologue
    int kk = beg + grp; if (kk > e1) kk = e1;
    int idx_c = csr_src[kk];
    uint2 raw_c = *reinterpret_cast<const uint2*>(xl + ((size_t)idx_c << 6) + c0);
    kk = beg + 4 + grp; if (kk > e1) kk = e1;
    int idx_n = csr_src[kk];
    for (int k0 = beg; k0 < end; k0 += 4) {
        // issue next-iteration loads before the shuffle chain
        uint2 raw_n = *reinterpret_cast<const uint2*>(xl + ((size_t)idx_n << 6) + c0);
        int kk2 = k0 + 8 + grp; if (kk2 > e1) kk2 = e1;
        int idx_n2 = csr_src[kk2];
        // compute on current
        float2 f01 = __half22float2(*reinterpret_cast<__half2*>(&raw_c.x));
        float2 f23 = __half22float2(*reinterpret_cast<__half2*>(&raw_c.y));
        float v0 = f01.x, v1 = f01.y, v2 = f23.x, v3 = f23.y;
        float t0 = v0 + xrv.x; t0 = (t0 > 0.f) ? t0 : 0.2f * t0;
        float t1 = v1 + xrv.y; t1 = (t1 > 0.f) ? t1 : 0.2f * t1;
        float t2 = v2 + xrv.z; t2 = (t2 > 0.f) ? t2 : 0.2f * t2;
        float t3 = v3 + xrv.w; t3 = (t3 > 0.f) ? t3 : 0.2f * t3;
        float p = fmaf(t3, attv.w, fmaf(t2, attv.z, fmaf(t1, attv.y, t0 * attv.x)));
        p += __shfl_xor(p, 1);
        p += __shfl_xor(p, 2);
        p += __shfl_xor(p, 4);
        p += __shfl_xor(p, 8);
        float p0 = __shfl(p, sub);
        float p1 = __shfl(p, 16 + sub);
        float p2 = __shfl(p, 32 + sub);
        float p3 = __shfl(p, 48 + sub);
        int rem = end - k0;
        if (rem < 4) {
            if (rem <= 1) p1 = -INFINITY;
            if (rem <= 2) p2 = -INFINITY;
            if (rem <= 3) p3 = -INFINITY;
        }
        float mx = fmaxf(fmaxf(fmaxf(p0, p1), fmaxf(p2, p3)), m);
        float sc = __expf(m - mx);
        float w0 = __expf(p0 - mx), w1 = __expf(p1 - mx);
        float w2 = __expf(p2 - mx), w3 = __expf(p3 - mx);
        float wm = (grp < 2) ? ((grp == 0) ? w0 : w1) : ((grp == 2) ? w2 : w3);
        s = s * sc + ((w0 + w1) + (w2 + w3));
        acc0 = fmaf(wm, v0, acc0 * sc);
        acc1 = fmaf(wm, v1, acc1 * sc);
        acc2 = fmaf(wm, v2, acc2 * sc);
        acc3 = fmaf(wm, v3, acc3 * sc);
        m = mx;
        raw_c = raw_n;
        idx_n = idx_n2;
    }
    acc0 += __shfl_xor(acc0, 16); acc0 += __shfl_xor(acc0, 32);
    acc1 += __shfl_xor(acc1, 16); acc1 += __shfl_xor(acc1, 32);
    acc2 += __shfl_xor(acc2, 16); acc2 += __shfl_xor(acc2, 32);
    acc3 += __shfl_xor(acc3, 16); acc3 += __shfl_xor(acc3, 32);
    float inv = 1.0f / s;
    float4 bv = *reinterpret_cast<const float4*>(bias + c0);
    float o0 = fmaf(acc0, inv, bv.x);
    float o1 = fmaf(acc1, inv, bv.y);
    float o2 = fmaf(acc2, inv, bv.z);
    float o3 = fmaf(acc3, inv, bv.w);
    if (do_relu) {
        o0 = fmaxf(o0, 0.f); o1 = fmaxf(o1, 0.f);
        o2 = fmaxf(o2, 0.f); o3 = fmaxf(o3, 0.f);
    }
    if (grp == 0) {
        *reinterpret_cast<float4*>(hout + (size_t)node * 64 + c0) =
            make_float4(o0, o1, o2, o3);
    }
}

// ---------------- MLP GEMM (R5 verbatim: register weights, staged rows) -----

template <int DIN, int DOUT, int BN_IN>
__global__ __launch_bounds__(256) void k_mlp_gemm(
        const float* __restrict__ hin, const float* __restrict__ W,
        const float* __restrict__ bias, float* __restrict__ z,
        float* __restrict__ stat_sum, float* __restrict__ stat_sq,
        const float* __restrict__ muI, const float* __restrict__ ivI,
        const float* __restrict__ gI, const float* __restrict__ beI,
        int n) {
    constexpr int COLS = DOUT / 64;          // outputs per thread (1 or 2)
    constexpr int F4PT = DIN / 64;           // staging float4s per thread (1 or 2)
    __shared__ float rows[16][DIN];
    __shared__ float red[256];
    int tid = threadIdx.x;
    int col = tid & 63, rlane = tid >> 6;
    float wreg[COLS][DIN];
    #pragma unroll
    for (int j = 0; j < COLS; ++j)
        #pragma unroll
        for (int k = 0; k < DIN; ++k)
            wreg[j][k] = W[k * DOUT + col + j * 64];
    float bc[COLS], ls[COLS], lq[COLS];
    #pragma unroll
    for (int j = 0; j < COLS; ++j) {
        bc[j] = bias[col + j * 64];
        ls[j] = 0.f; lq[j] = 0.f;
    }
    // staging geometry + optional BN coeffs for the staged columns
    int srT[F4PT], scT[F4PT];
    float4 An[F4PT], Bn[F4PT];
    #pragma unroll
    for (int i = 0; i < F4PT; ++i) {
        int idx = tid + i * 256;
        srT[i] = idx / (DIN / 4);
        scT[i] = (idx % (DIN / 4)) * 4;
        if (BN_IN) {
            int c = scT[i];
            float4 iv4 = *reinterpret_cast<const float4*>(ivI + c);
            float4 g4  = *reinterpret_cast<const float4*>(gI + c);
            float4 mu4 = *reinterpret_cast<const float4*>(muI + c);
            float4 be4 = *reinterpret_cast<const float4*>(beI + c);
            An[i].x = iv4.x * g4.x; Bn[i].x = be4.x - mu4.x * An[i].x;
            An[i].y = iv4.y * g4.y; Bn[i].y = be4.y - mu4.y * An[i].y;
            An[i].z = iv4.z * g4.z; Bn[i].z = be4.z - mu4.z * An[i].z;
            An[i].w = iv4.w * g4.w; Bn[i].w = be4.w - mu4.w * An[i].w;
        }
    }
    for (int r0 = blockIdx.x * 16; r0 < n; r0 += gridDim.x * 16) {
        #pragma unroll
        for (int i = 0; i < F4PT; ++i) {
            int rr = r0 + srT[i];
            float4 v = make_float4(0.f, 0.f, 0.f, 0.f);
            if (rr < n) v = *reinterpret_cast<const float4*>(hin + (size_t)rr * DIN + scT[i]);
            if (BN_IN) {
                v.x = fmaxf(fmaf(v.x, An[i].x, Bn[i].x), 0.f);
                v.y = fmaxf(fmaf(v.y, An[i].y, Bn[i].y), 0.f);
                v.z = fmaxf(fmaf(v.z, An[i].z, Bn[i].z), 0.f);
                v.w = fmaxf(fmaf(v.w, An[i].w, Bn[i].w), 0.f);
            }
            *reinterpret_cast<float4*>(&rows[srT[i]][scT[i]]) = v;
        }
        __syncthreads();
        #pragma unroll
        for (int q = 0; q < 4; ++q) {
            int rI = rlane * 4 + q;
            int r = r0 + rI;
            float a[COLS];
            #pragma unroll
            for (int j = 0; j < COLS; ++j) a[j] = bc[j];
            const float4* rv = reinterpret_cast<const float4*>(rows[rI]);
            #pragma unroll
            for (int k4 = 0; k4 < DIN / 4; ++k4) {
                float4 h4 = rv[k4];
                #pragma unroll
                for (int j = 0; j < COLS; ++j) {
                    a[j] = fmaf(h4.x, wreg[j][k4 * 4 + 0], a[j]);
                    a[j] = fmaf(h4.y, wreg[j][k4 * 4 + 1], a[j]);
                    a[j] = fmaf(h4.z, wreg[j][k4 * 4 + 2], a[j]);
                    a[j] = fmaf(h4.w, wreg[j][k4 * 4 + 3], a[j]);
                }
            }
            if (r < n) {
                #pragma unroll
                for (int j = 0; j < COLS; ++j) {
                    z[(size_t)r * DOUT + col + j * 64] = a[j];
                    ls[j] += a[j];
                    lq[j] = fmaf(a[j], a[j], lq[j]);
                }
            }
        }
        __syncthreads();
    }
    // block reduce of BN stats: 4 row-lanes share each column
    #pragma unroll
    for (int j = 0; j < COLS; ++j) {
        __syncthreads();
        red[tid] = ls[j];
        __syncthreads();
        if (rlane == 0) {
            float t = red[col] + red[col + 64] + red[col + 128] + red[col + 192];
            atomicAdd(&stat_sum[col + j * 64], t);
        }
        __syncthreads();
        red[tid] = lq[j];
        __syncthreads();
        if (rlane == 0) {
            float t = red[col] + red[col + 64] + red[col + 128] + red[col + 192];
            atomicAdd(&stat_sq[col + j * 64], t);
        }
    }
}

__global__ void k_bn_fin(const float* __restrict__ ssum, const float* __restrict__ ssq,
                         float* __restrict__ mu, float* __restrict__ inv,
                         int n, int dout) {
    int c = threadIdx.x;
    if (c >= dout) return;
    float m = ssum[c] / (float)n;
    float v = ssq[c] / (float)n - m * m;
    mu[c]  = m;
    inv[c] = rsqrtf(fmaxf(v, 0.f) + 1e-5f);
}

// ---------------- fused BN1+ReLU + final linear (64->1) + segmented mean-pool -

__global__ __launch_bounds__(256) void k_pool_seg(
        const float* __restrict__ h2, const float* __restrict__ w2,
        const float* __restrict__ b2, const int* __restrict__ batch,
        const float* __restrict__ mu1, const float* __restrict__ iv1,
        const float* __restrict__ g1, const float* __restrict__ be1,
        float* __restrict__ out, int n) {
    int g = blockIdx.x;
    int tid = threadIdx.x;
    int lo = 0, hi = n;
    while (lo < hi) { int mid = (lo + hi) >> 1; if (batch[mid] < g) lo = mid + 1; else hi = mid; }
    int start = lo;
    hi = n;
    while (lo < hi) { int mid = (lo + hi) >> 1; if (batch[mid] < g + 1) lo = mid + 1; else hi = mid; }
    int end = lo;
    int cnt = end - start;

    int c = (tid << 2) & 63;
    float A0 = iv1[c] * g1[c],         B0 = be1[c] - mu1[c] * A0;
    float A1 = iv1[c + 1] * g1[c + 1], B1 = be1[c + 1] - mu1[c + 1] * A1;
    float A2 = iv1[c + 2] * g1[c + 2], B2 = be1[c + 2] - mu1[c + 2] * A2;
    float A3 = iv1[c + 3] * g1[c + 3], B3 = be1[c + 3] - mu1[c + 3] * A3;
    float wa = w2[c], wb = w2[c + 1], wc = w2[c + 2], wd = w2[c + 3];
    const float4* b4 = reinterpret_cast<const float4*>(h2 + (size_t)start * 64);
    long total4 = (long)cnt * 16;
    float acc = 0.f;
    for (long i = tid; i < total4; i += 256) {
        float4 v = b4[i];
        acc = fmaf(fmaxf(fmaf(v.x, A0, B0), 0.f), wa, acc);
        acc = fmaf(fmaxf(fmaf(v.y, A1, B1), 0.f), wb, acc);
        acc = fmaf(fmaxf(fmaf(v.z, A2, B2), 0.f), wc, acc);
        acc = fmaf(fmaxf(fmaf(v.w, A3, B3), 0.f), wd, acc);
    }
    __shared__ float red[256];
    red[tid] = acc; __syncthreads();
    for (int off = 128; off; off >>= 1) {
        if (tid < off) red[tid] += red[tid + off];
        __syncthreads();
    }
    if (tid == 0) out[g] = (cnt > 0) ? red[0] / (float)cnt + b2[0] : 0.f;
}

// ---------------------------------------------------------------------------

extern "C" void kernel_launch(void* const* d_in, const int* in_sizes, int n_in,
                              void* d_out, int out_size, void* d_ws, size_t ws_size,
                              hipStream_t stream) {
    const float* x     = (const float*)d_in[0];
    const int*   ei    = (const int*)d_in[1];
    const int*   batch = (const int*)d_in[2];

    const int N = in_sizes[0] / 64;
    const int E = in_sizes[1] / 2;
    const int G = out_size;
    const int Etot = E + N;
    const int NB = (N + BSIZE - 1) >> BSHIFT;

    const int* srcA = ei;
    const int* dstA = ei + E;

    const float* Wl[3]; const float* bl[3]; const float* Wr[3];
    const float* br[3]; const float* att[3]; const float* bb[3];
    for (int l = 0; l < 3; ++l) {
        int base = 3 + 6 * l;
        Wl[l]  = (const float*)d_in[base + 0];
        bl[l]  = (const float*)d_in[base + 1];
        Wr[l]  = (const float*)d_in[base + 2];
        br[l]  = (const float*)d_in[base + 3];
        att[l] = (const float*)d_in[base + 4];
        bb[l]  = (const float*)d_in[base + 5];
    }
    const float* mW0 = (const float*)d_in[21];
    const float* mb0 = (const float*)d_in[22];
    const float* g0  = (const float*)d_in[23];
    const float* be0 = (const float*)d_in[24];
    const float* mW1 = (const float*)d_in[25];
    const float* mb1 = (const float*)d_in[26];
    const float* g1  = (const float*)d_in[27];
    const float* be1 = (const float*)d_in[28];
    const float* mW2 = (const float*)d_in[29];
    const float* mb2 = (const float*)d_in[30];

    // ---- workspace carve ----
    char* w = (char*)d_ws;
    auto alloc = [&](size_t bytes) -> void* {
        void* p = (void*)w;
        w += (bytes + 255) & ~(size_t)255;
        return p;
    };
    int*    rowptr = (int*)alloc((size_t)(N + 1) * 4);
    int*    csr    = (int*)alloc((size_t)Etot * 4);
    int*    bcnt   = (int*)alloc(512 * 4);
    int*    bbase  = (int*)alloc(520 * 4);
    int*    bcur   = (int*)alloc(512 * 4);
    // xl(half,12.8MB) + xr(f32,25.6MB) + zext(12.8MB) contiguous; z spans them
    __half* xl     = (__half*)alloc((size_t)N * 64 * 2);
    float*  xr     = (float*)alloc((size_t)N * 64 * 4);
    float*  zext   = (float*)alloc((size_t)N * 32 * 4);
    float*  h      = (float*)alloc((size_t)N * 64 * 4);
    float*  stats  = (float*)alloc(8 * 128 * 4);
    float*  z      = (float*)xl;          // [N,128] fp32 spans xl+xr+zext
    unsigned* ebuf = (unsigned*)h;        // dead before h is live
    (void)zext;

    float* sum0 = stats;        float* sq0 = stats + 128;
    float* mu0  = stats + 256;  float* iv0 = stats + 384;
    float* sum1 = stats + 512;  float* sq1 = stats + 640;
    float* mu1  = stats + 768;  float* iv1 = stats + 896;

    // ---- bucketed CSR build ----
    hipMemsetAsync(bcnt, 0, 512 * 4, stream);
    k_bcount<<<256, 256, 0, stream>>>(dstA, bcnt, E, N);
    k_bscan<<<1, 512, 0, stream>>>(bcnt, bbase, bcur, rowptr, NB, N, Etot);
    k_bpart<<<256, 256, 0, stream>>>(srcA, dstA, bcur, ebuf, E, N);
    k_bfill<<<NB, 512, 0, stream>>>(ebuf, bbase, rowptr, csr, N, NB);

    // ---- 3x GATv2 ----
    int nodeBlocks = (N + 3) / 4;
    int bppG = (N + 63) / 64;            // single-pass per panel
    const float* hin = x;
    for (int l = 0; l < 3; ++l) {
        k_gat_gemm<<<2 * bppG, 256, 0, stream>>>(hin, Wl[l], bl[l], Wr[l], br[l],
                                                 xl, xr, N);
        k_gat_edge<<<nodeBlocks, 256, 0, stream>>>(xl, xr, rowptr, csr,
                                                   att[l], bb[l], h, N,
                                                   (l < 2) ? 1 : 0);
        hin = h;
    }

    // ---- MLP layer 0: 64 -> 128 (stats for BN0) ----
    hipMemsetAsync(sum0, 0, 2 * 128 * 4, stream);
    k_mlp_gemm<64, 128, 0><<<2048, 256, 0, stream>>>(
        h, mW0, mb0, z, sum0, sq0, nullptr, nullptr, nullptr, nullptr, N);
    k_bn_fin<<<1, 128, 0, stream>>>(sum0, sq0, mu0, iv0, N, 128);

    // ---- MLP layer 1: 128 -> 64, BN0+ReLU fused into staging ----
    hipMemsetAsync(sum1, 0, 2 * 128 * 4, stream);
    k_mlp_gemm<128, 64, 1><<<2048, 256, 0, stream>>>(
        z, mW1, mb1, h, sum1, sq1, mu0, iv0, g0, be0, N);
    k_bn_fin<<<1, 64, 0, stream>>>(sum1, sq1, mu1, iv1, N, 64);

    // ---- fused BN1+ReLU + final linear + segmented mean pool ----
    k_pool_seg<<<G, 256, 0, stream>>>(h, mW2, mb2, batch, mu1, iv1, g1, be1,
                                      (float*)d_out, N);
}